// Round 20
// baseline (346.395 us; speedup 1.0000x reference)
//
#include <hip/hip_runtime.h>

#define NIN 10517
typedef unsigned short ushort_t;
using f32x4  = __attribute__((ext_vector_type(4))) float;
using bf16x8 = __attribute__((ext_vector_type(8))) short;

__device__ __forceinline__ float lrelu02(float x){ return x > 0.f ? x : 0.2f*x; }
__device__ __forceinline__ float fast_tanh(float x){ float e=__expf(2.f*x); return 1.f - 2.f/(e+1.f); }
__device__ __forceinline__ float fast_sig(float x){ return 1.f/(1.f+__expf(-x)); }

__device__ __forceinline__ ushort_t f2bf(float x){
  unsigned u = __float_as_uint(x);
  unsigned r = u + 0x7FFF + ((u >> 16) & 1);
  return (ushort_t)(r >> 16);
}
__device__ __forceinline__ float bf2f(ushort_t v){ return __uint_as_float(((unsigned)v) << 16); }

// lgkm-only barrier; the "memory" clobber is ALSO the fence that pins each
// phase's weight-load ISSUE into that phase (loads cannot sink across it) --
// this is what makes the one-phase-ahead weight pipeline in k_rnn stick.
#define LBAR() do { asm volatile("s_waitcnt lgkmcnt(0)" ::: "memory"); \
                    __builtin_amdgcn_s_barrier(); } while (0)

// ---------------- K1a: FC + GAT-Wh0 + s,d — MFMA GEMMs (16 rows/block, 128 blocks) ----------------
__global__ __launch_bounds__(256) void k_fc_gat(const float* __restrict__ inputs,
    const float* __restrict__ fc_w, const float* __restrict__ fc_b,
    const float* __restrict__ gat_w, const float* __restrict__ a_src, const float* __restrict__ a_dst,
    const float* __restrict__ ode_w1, const float* __restrict__ ode_w2, const float* __restrict__ gru_wh,
    const float* __restrict__ act_w, const float* __restrict__ gru_wi,
    float* __restrict__ wh0_ws, float* __restrict__ sd_ws,
    ushort_t* __restrict__ w1B, ushort_t* __restrict__ w2B, ushort_t* __restrict__ ghB,
    ushort_t* __restrict__ actB, ushort_t* __restrict__ wiBt,
    ushort_t* __restrict__ fc_wB, ushort_t* __restrict__ gat_wB)
{
  __shared__ __align__(16) ushort_t xinB[16][392];
  __shared__ __align__(16) ushort_t xfcB[16][264];
  __shared__ float wh[16][132];
  const int tid = threadIdx.x;
  const int bt0 = blockIdx.x * 16;

  for (int p = blockIdx.x * 256 + tid; p < 280576; p += 128*256) {
    if (p < 49152) {
      int m = p >> 7, k = p & 127;
      ghB[p] = f2bf(gru_wh[k*384 + m]);
    } else if (p < 65536) {
      int q = p - 49152, jj = q >> 7, k = q & 127;
      w1B[q] = f2bf(ode_w1[k*128 + jj]);
    } else if (p < 81920) {
      int q = p - 65536, jj = q >> 7, k = q & 127;
      w2B[q] = f2bf(ode_w2[k*128 + jj]);
    } else if (p < 100352) {
      int q = p - 81920, col = q >> 7, k = q & 127;
      actB[q] = (col < 132) ? f2bf(act_w[k*132 + col]) : (ushort_t)0;
    } else if (p < 149504) {
      int q = p - 100352, m = q >> 7, f = q & 127;
      wiBt[q] = f2bf(gru_wi[f*384 + m]);
    } else if (p < 247808) {
      int q = p - 149504, col = q / 384, k = q - col*384;
      fc_wB[q] = f2bf(fc_w[k*256 + col]);
    } else {
      int q = p - 247808, col = q >> 8, k = q & 255;
      gat_wB[q] = f2bf(gat_w[k*128 + col]);
    }
  }

  for (int idx = tid; idx < 16*384; idx += 256) {
    int r = idx / 384, f = idx - r*384;
    xinB[r][f] = f2bf(inputs[(size_t)(bt0+r)*NIN + 10133 + f]);
  }
  __syncthreads();

  const int w = tid >> 6, lane = tid & 63;
  const int li = lane & 15, g = lane >> 4;

  // FC: xfc = relu(xin @ fc_w + fc_b)
  {
    bf16x8 afr[12];
    #pragma unroll
    for (int kt=0;kt<12;kt++)
      afr[kt] = *reinterpret_cast<const bf16x8*>(&xinB[li][kt*32 + g*8]);
    for (int ct = w*4; ct < w*4 + 4; ct++) {
      f32x4 acc = {0.f,0.f,0.f,0.f};
      #pragma unroll
      for (int kt=0;kt<12;kt++){
        bf16x8 bf = *reinterpret_cast<const bf16x8*>(fc_wB + (size_t)(ct*16+li)*384 + kt*32 + g*8);
        acc = __builtin_amdgcn_mfma_f32_16x16x32_bf16(afr[kt], bf, acc, 0,0,0);
      }
      const float bias = fc_b[ct*16 + li];
      #pragma unroll
      for (int r=0;r<4;r++)
        xfcB[g*4 + r][ct*16 + li] = f2bf(fmaxf(acc[r] + bias, 0.f));
    }
  }
  __syncthreads();

  // GAT: wh = xfc @ gat_w
  {
    bf16x8 afr[8];
    #pragma unroll
    for (int kt=0;kt<8;kt++)
      afr[kt] = *reinterpret_cast<const bf16x8*>(&xfcB[li][kt*32 + g*8]);
    for (int ct = w*2; ct < w*2 + 2; ct++) {
      f32x4 acc = {0.f,0.f,0.f,0.f};
      #pragma unroll
      for (int kt=0;kt<8;kt++){
        bf16x8 bf = *reinterpret_cast<const bf16x8*>(gat_wB + (size_t)(ct*16+li)*256 + kt*32 + g*8);
        acc = __builtin_amdgcn_mfma_f32_16x16x32_bf16(afr[kt], bf, acc, 0,0,0);
      }
      #pragma unroll
      for (int r=0;r<4;r++){
        const int row = g*4 + r, col = ct*16 + li;
        wh[row][col] = acc[r];
        wh0_ws[(size_t)(bt0+row)*128 + col] = acc[r];
      }
    }
  }
  __syncthreads();

  if (tid < 128) {
    const int r = tid >> 3, h = (tid >> 1) & 3, wv = tid & 1;
    const float* av = wv ? a_dst : a_src;
    float acc = 0.f;
    #pragma unroll
    for (int d=0; d<32; d++) acc = fmaf(wh[r][h*32+d], av[h*32+d], acc);
    sd_ws[(size_t)(bt0+r)*8 + wv*4 + h] = acc;
  }
}

// ---------------- K1b: adjacency stats + closed-form alpha + x_gat (bf16 out) ----------------
__global__ __launch_bounds__(256) void k_alpha_gi(const float* __restrict__ inputs,
    const float* __restrict__ wh0_ws, const float* __restrict__ sd_ws,
    ushort_t* __restrict__ xg_bf)
{
  __shared__ int cnt[100];
  __shared__ int a0f[100];
  __shared__ float alpha[4][100];
  __shared__ float wh0[128];
  __shared__ float sdl[8];
  __shared__ float psum[256];
  const int tid = threadIdx.x;
  const size_t bt = blockIdx.x;
  if (tid < 128) wh0[tid] = wh0_ws[bt*128 + tid];
  if (tid < 8) sdl[tid] = sd_ws[bt*8 + tid];
  const float* adj = inputs + bt*NIN + 132;
  const int wv = tid >> 6, lane = tid & 63;
  for (int i = wv; i < 100; i += 4) {
    float v0 = adj[i*100 + lane];
    int pred0 = (lane != 0) && ((v0 > 0.f) || (lane == i));
    unsigned long long b0 = __ballot(pred0);
    int pred1 = 0;
    if (lane < 36) {
      float v1 = adj[i*100 + 64 + lane];
      pred1 = (v1 > 0.f) || ((64 + lane) == i);
    }
    unsigned long long b1 = __ballot(pred1);
    if (lane == 0) {
      cnt[i] = __popcll(b0) + __popcll(b1);
      a0f[i] = (v0 > 0.f) ? 1 : 0;
    }
  }
  __syncthreads();
  for (int idx = tid; idx < 400; idx += 256) {
    int h = idx / 100, i = idx - h*100;
    float s = sdl[h], d = sdl[4+h];
    float a;
    if (i == 0) {
      float ea = __expf(lrelu02(s + d));
      float eb = __expf(lrelu02(s));
      a = ea / (ea + (float)cnt[0] * eb);
    } else if (a0f[i]) {
      float ed = __expf(lrelu02(d));
      a = ed / (ed + (float)cnt[i]);
    } else {
      a = 0.f;
    }
    alpha[h][i] = a;
  }
  __syncthreads();
  {
    const int pr = tid & 127, hf = tid >> 7;
    const float w = wh0[pr];
    const int hh = pr >> 5;
    float sum = 0.f;
    const int i0 = hf * 50;
    for (int i = i0; i < i0 + 50; i++) {
      float t = alpha[hh][i] * w;
      sum += (t > 0.f) ? t : (__expf(t) - 1.f);
    }
    psum[tid] = sum;
  }
  __syncthreads();
  if (tid < 128) xg_bf[bt*128 + tid] = f2bf((psum[tid] + psum[tid+128]) * 0.01f);
}

// ---------------- K1c: gi = xg @ gru_wi + bi as MFMA GEMM (2048x384x128) ----------------
__global__ __launch_bounds__(256) void k_gi(const ushort_t* __restrict__ xg_bf,
    const ushort_t* __restrict__ wiBt, const float* __restrict__ gru_bi,
    float* __restrict__ gi_ws)
{
  const int tid = threadIdx.x;
  const int w = tid >> 6, lane = tid & 63;
  const int li = lane & 15, g = lane >> 4;
  const int bt0 = blockIdx.x * 16;
  bf16x8 haf[4];
  #pragma unroll
  for (int kt=0;kt<4;kt++)
    haf[kt] = *reinterpret_cast<const bf16x8*>(xg_bf + ((size_t)(bt0 + li))*128 + kt*32 + g*8);
  for (int ct = w*6; ct < w*6 + 6; ct++) {
    const int m = ct*16 + li;
    const f32x4 z0 = {0.f,0.f,0.f,0.f};
    const ushort_t* wb = wiBt + (size_t)m*128;
    bf16x8 b0 = *reinterpret_cast<const bf16x8*>(wb + 0*32 + g*8);
    bf16x8 b1f = *reinterpret_cast<const bf16x8*>(wb + 1*32 + g*8);
    bf16x8 b2f = *reinterpret_cast<const bf16x8*>(wb + 2*32 + g*8);
    bf16x8 b3f = *reinterpret_cast<const bf16x8*>(wb + 3*32 + g*8);
    f32x4 c0 = __builtin_amdgcn_mfma_f32_16x16x32_bf16(haf[0], b0,  z0, 0,0,0);
    f32x4 c1 = __builtin_amdgcn_mfma_f32_16x16x32_bf16(haf[1], b1f, z0, 0,0,0);
    f32x4 c2 = __builtin_amdgcn_mfma_f32_16x16x32_bf16(haf[2], b2f, z0, 0,0,0);
    f32x4 c3 = __builtin_amdgcn_mfma_f32_16x16x32_bf16(haf[3], b3f, z0, 0,0,0);
    const float bim = gru_bi[m];
    #pragma unroll
    for (int r=0;r<4;r++)
      gi_ws[(size_t)(bt0 + g*4 + r)*384 + m] = ((c0[r]+c1[r]) + (c2[r]+c3[r])) + bim;
  }
}

// ---------------- K2: RK4-ODE + GRU scan via MFMA, weight loads pipelined 1 phase ahead ----------------
// r14/r18 structure + this round's change: each phase issues the NEXT phase's
// weight-fragment loads (Wa/Wb alternate; ph8 bursts GA/GB/GC; ph9 reloads
// W1). The LBAR memory clobber pins issue into the phase -> ~500cy lead vs
// the ~220cy L2 latency that was exposed on the serial chain (VGPR=68 showed
// loads were issued in the consuming phase with only ~100cy cover).
__global__ __launch_bounds__(512, 2) void k_rnn(const float* __restrict__ inputs,
    const float* __restrict__ h0,
    const ushort_t* __restrict__ w1B, const float* __restrict__ ode_b1,
    const ushort_t* __restrict__ w2B, const float* __restrict__ ode_b2,
    const ushort_t* __restrict__ ghB, const float* __restrict__ gru_bh,
    const ushort_t* __restrict__ actB, const float* __restrict__ act_b,
    const float* __restrict__ val_w, const float* __restrict__ val_b,
    const float* __restrict__ gi_ws,
    float* __restrict__ out_logits, float* __restrict__ out_hT, float* __restrict__ out_val)
{
  __shared__ __align__(16) ushort_t bufA[128];
  __shared__ __align__(16) ushort_t bufB[128];
  __shared__ __align__(16) ushort_t bufC[128];
  __shared__ float dtbuf[64];
  __shared__ __align__(16) ushort_t hsbuf[64*136];
  const int tid = threadIdx.x;
  const int b = blockIdx.x;
  const int w = tid >> 6, lane = tid & 63;
  const int li = lane & 15, g = lane >> 4;
  const int col = w*16 + li;

  const ushort_t* p_w1 = w1B + col*128;
  const ushort_t* p_w2 = w2B + col*128;
  const ushort_t* p_ga = ghB + (size_t)col*128;
  const ushort_t* p_gb = ghB + (size_t)(col+128)*128;
  const ushort_t* p_gc = ghB + (size_t)(col+256)*128;

  const float b1 = ode_b1[col], b2 = ode_b2[col];
  const float bh0 = gru_bh[col], bh1 = gru_bh[col+128], bh2 = gru_bh[col+256];
  float h = h0[b*128 + col];
  if (tid < 64) dtbuf[tid] = inputs[((size_t)b*64 + tid)*NIN + 10132];
  if (lane < 16) bufC[col] = f2bf(h);
  const float* gib = gi_ws + (size_t)b*64*384 + col;
  __syncthreads();

  bf16x8 af[4];
  auto ldaf = [&](const ushort_t* __restrict__ hb){
    #pragma unroll
    for (int kt=0;kt<4;kt++) af[kt] = *reinterpret_cast<const bf16x8*>(hb + kt*32 + g*8);
  };
  auto ldw = [&](bf16x8 (&d)[4], const ushort_t* __restrict__ src){
    #pragma unroll
    for (int kt=0;kt<4;kt++) d[kt] = *reinterpret_cast<const bf16x8*>(src + kt*32 + g*8);
  };
  auto mvac = [&](const bf16x8 (&Wf)[4])->float{
    const f32x4 z0 = {0.f,0.f,0.f,0.f};
    f32x4 c0 = __builtin_amdgcn_mfma_f32_16x16x32_bf16(af[0], Wf[0], z0, 0,0,0);
    f32x4 c1 = __builtin_amdgcn_mfma_f32_16x16x32_bf16(af[1], Wf[1], z0, 0,0,0);
    f32x4 c2 = __builtin_amdgcn_mfma_f32_16x16x32_bf16(af[2], Wf[2], z0, 0,0,0);
    f32x4 c3 = __builtin_amdgcn_mfma_f32_16x16x32_bf16(af[3], Wf[3], z0, 0,0,0);
    return (c0[0]+c1[0]) + (c2[0]+c3[0]);
  };

  bf16x8 Wa[4], Wb[4], GAf[4], GBf[4], GCf[4];
  ldw(Wa, p_w1);   // prologue: ph1's weights

  for (int t=0; t<64; t++) {
    const float dt = dtbuf[t];
    const float gir = gib[(size_t)t*384];
    const float giz = gib[(size_t)t*384 + 128];
    const float gin = gib[(size_t)t*384 + 256];

    float u, k1, k2, k3, k4;
    // ph1: use Wa(W1), prefetch Wb(W2)
    ldaf(bufC); ldw(Wb, p_w2); u  = fast_tanh(mvac(Wa)+b1); if (lane<16) bufA[col]=f2bf(u);                  LBAR();
    // ph2: use Wb(W2), prefetch Wa(W1)
    ldaf(bufA); ldw(Wa, p_w1); k1 = fast_tanh(mvac(Wb)+b2); if (lane<16) bufB[col]=f2bf(fmaf(0.5f*dt,k1,h)); LBAR();
    // ph3
    ldaf(bufB); ldw(Wb, p_w2); u  = fast_tanh(mvac(Wa)+b1); if (lane<16) bufA[col]=f2bf(u);                  LBAR();
    // ph4
    ldaf(bufA); ldw(Wa, p_w1); k2 = fast_tanh(mvac(Wb)+b2); if (lane<16) bufB[col]=f2bf(fmaf(0.5f*dt,k2,h)); LBAR();
    // ph5
    ldaf(bufB); ldw(Wb, p_w2); u  = fast_tanh(mvac(Wa)+b1); if (lane<16) bufA[col]=f2bf(u);                  LBAR();
    // ph6
    ldaf(bufA); ldw(Wa, p_w1); k3 = fast_tanh(mvac(Wb)+b2); if (lane<16) bufB[col]=f2bf(fmaf(dt,k3,h));      LBAR();
    // ph7
    ldaf(bufB); ldw(Wb, p_w2); u  = fast_tanh(mvac(Wa)+b1); if (lane<16) bufA[col]=f2bf(u);                  LBAR();
    // ph8: use Wb(W2), prefetch gh triplet
    ldaf(bufA); ldw(GAf, p_ga); ldw(GBf, p_gb); ldw(GCf, p_gc);
    k4 = fast_tanh(mvac(Wb)+b2);
    const float h_ode = fmaf(dt*(1.f/6.f), (k1 + 2.f*k2) + (2.f*k3 + k4), h);
    if (lane<16) bufB[col] = f2bf(h_ode);                                                                    LBAR();
    // ph9: use gh triplet, prefetch Wa(W1) for next step's ph1
    ldaf(bufB); ldw(Wa, p_w1);
    {
      const float r = fast_sig(gir + mvac(GAf) + bh0);
      const float z = fast_sig(giz + mvac(GBf) + bh1);
      const float n = fast_tanh(gin + r*(mvac(GCf) + bh2));
      h = (1.f - z)*n + z*h_ode;
    }
    if (lane < 16) {
      bufC[col] = f2bf(h);
      hsbuf[t*136 + col] = f2bf(h);
    }
    LBAR();
  }

  if (lane < 16) out_hT[b*128 + col] = h;

  // ---- epilogue: logits via MFMA GEMM (64x132 = hs @ act_w) ----
  {
    const int rt = w & 3, ch = w >> 2;
    const int r0 = rt*16;
    bf16x8 haf[4];
    #pragma unroll
    for (int kt=0;kt<4;kt++)
      haf[kt] = *reinterpret_cast<const bf16x8*>(hsbuf + (r0+li)*136 + kt*32 + g*8);
    const int ct0 = ch ? 5 : 0, ctN = ch ? 9 : 5;
    for (int ct=ct0; ct<ctN; ct++){
      const f32x4 z0 = {0.f,0.f,0.f,0.f};
      f32x4 c0, c1, c2, c3;
      {
        const ushort_t* ab = actB + (size_t)(ct*16+li)*128;
        bf16x8 b0 = *reinterpret_cast<const bf16x8*>(ab + 0*32 + g*8);
        bf16x8 b1f = *reinterpret_cast<const bf16x8*>(ab + 1*32 + g*8);
        bf16x8 b2f = *reinterpret_cast<const bf16x8*>(ab + 2*32 + g*8);
        bf16x8 b3f = *reinterpret_cast<const bf16x8*>(ab + 3*32 + g*8);
        c0 = __builtin_amdgcn_mfma_f32_16x16x32_bf16(haf[0], b0,  z0, 0,0,0);
        c1 = __builtin_amdgcn_mfma_f32_16x16x32_bf16(haf[1], b1f, z0, 0,0,0);
        c2 = __builtin_amdgcn_mfma_f32_16x16x32_bf16(haf[2], b2f, z0, 0,0,0);
        c3 = __builtin_amdgcn_mfma_f32_16x16x32_bf16(haf[3], b3f, z0, 0,0,0);
      }
      const int colL = ct*16 + li;
      if (colL < 132){
        const float ab = act_b[colL];
        #pragma unroll
        for (int reg=0; reg<4; reg++){
          const int r = r0 + g*4 + reg;
          const size_t bt = (size_t)b*64 + r;
          const float mval = inputs[bt*NIN + colL];
          const float v = ((c0[reg]+c1[reg]) + (c2[reg]+c3[reg])) + ab;
          out_logits[bt*132 + colL] = (mval == 0.f) ? -1e10f : v;
        }
      }
    }
  }
  // ---- epilogue: value head ----
  if (tid < 64){
    float acc = val_b[0];
    for (int k=0;k<128;k++) acc = fmaf(bf2f(hsbuf[tid*136 + k]), val_w[k], acc);
    out_val[b*64 + tid] = acc;
  }
}

extern "C" void kernel_launch(void* const* d_in, const int* in_sizes, int n_in,
                              void* d_out, int out_size, void* d_ws, size_t ws_size,
                              hipStream_t stream) {
  (void)in_sizes; (void)n_in; (void)out_size; (void)ws_size;
  const float* inputs = (const float*)d_in[0];
  const float* h0     = (const float*)d_in[1];
  const float* fc_w   = (const float*)d_in[2];
  const float* fc_b   = (const float*)d_in[3];
  const float* gat_w  = (const float*)d_in[4];
  const float* a_src  = (const float*)d_in[5];
  const float* a_dst  = (const float*)d_in[6];
  const float* ode_w1 = (const float*)d_in[7];
  const float* ode_b1 = (const float*)d_in[8];
  const float* ode_w2 = (const float*)d_in[9];
  const float* ode_b2 = (const float*)d_in[10];
  const float* gru_wi = (const float*)d_in[11];
  const float* gru_wh = (const float*)d_in[12];
  const float* gru_bi = (const float*)d_in[13];
  const float* gru_bh = (const float*)d_in[14];
  const float* act_w  = (const float*)d_in[15];
  const float* act_b  = (const float*)d_in[16];
  const float* val_w  = (const float*)d_in[17];
  const float* val_b  = (const float*)d_in[18];

  float* ws   = (float*)d_ws;
  float* wh0  = ws;                              // 262144 floats
  float* sd   = ws + 262144;                     // 16384
  ushort_t* xg_bf = (ushort_t*)(ws + 278528);    // 262144 ush
  float* gi   = ws + 409600;                     // 786432 fl
  ushort_t* w1B   = (ushort_t*)(ws + 1196032);   // 16384 ush
  ushort_t* w2B   = (ushort_t*)(ws + 1204224);   // 16384 ush
  ushort_t* ghB   = (ushort_t*)(ws + 1212416);   // 49152 ush
  ushort_t* actB  = (ushort_t*)(ws + 1236992);   // 18432 ush
  ushort_t* wiBt  = (ushort_t*)(ws + 1246208);   // 49152 ush
  ushort_t* fc_wB = (ushort_t*)(ws + 1270784);   // 98304 ush
  ushort_t* gat_wB= (ushort_t*)(ws + 1319936);   // 32768 ush

  float* out        = (float*)d_out;
  float* out_logits = out;            // 2048*132
  float* out_hT     = out + 270336;   // 32*128
  float* out_val    = out + 274432;   // 2048

  k_fc_gat  <<<dim3(128),  dim3(256), 0, stream>>>(inputs, fc_w, fc_b, gat_w, a_src, a_dst,
                                                   ode_w1, ode_w2, gru_wh, act_w, gru_wi,
                                                   wh0, sd, w1B, w2B, ghB, actB, wiBt,
                                                   fc_wB, gat_wB);
  k_alpha_gi<<<dim3(2048), dim3(256), 0, stream>>>(inputs, wh0, sd, xg_bf);
  k_gi      <<<dim3(128),  dim3(256), 0, stream>>>(xg_bf, wiBt, gru_bi, gi);
  k_rnn     <<<dim3(32),   dim3(512), 0, stream>>>(inputs, h0, w1B, ode_b1, w2B, ode_b2,
                                                   ghB, gru_bh, actB, act_b, val_w, val_b,
                                                   gi, out_logits, out_hT, out_val);
}

// Round 21
// 204.882 us; speedup vs baseline: 1.6907x; 1.6907x over previous
//
#include <hip/hip_runtime.h>

#define NIN 10517
typedef unsigned short ushort_t;
using f32x4  = __attribute__((ext_vector_type(4))) float;
using bf16x8 = __attribute__((ext_vector_type(8))) short;

__device__ __forceinline__ float lrelu02(float x){ return x > 0.f ? x : 0.2f*x; }
__device__ __forceinline__ float fast_tanh(float x){ float e=__expf(2.f*x); return 1.f - 2.f/(e+1.f); }
__device__ __forceinline__ float fast_sig(float x){ return 1.f/(1.f+__expf(-x)); }

__device__ __forceinline__ ushort_t f2bf(float x){
  unsigned u = __float_as_uint(x);
  unsigned r = u + 0x7FFF + ((u >> 16) & 1);
  return (ushort_t)(r >> 16);
}
__device__ __forceinline__ float bf2f(ushort_t v){ return __uint_as_float(((unsigned)v) << 16); }

#define LBAR() do { asm volatile("s_waitcnt lgkmcnt(0)" ::: "memory"); \
                    __builtin_amdgcn_s_barrier(); } while (0)

// ---------------- K1a: FC + GAT-Wh0 + s,d — MFMA GEMMs (16 rows/block, 128 blocks) ----------------
__global__ __launch_bounds__(256) void k_fc_gat(const float* __restrict__ inputs,
    const float* __restrict__ fc_w, const float* __restrict__ fc_b,
    const float* __restrict__ gat_w, const float* __restrict__ a_src, const float* __restrict__ a_dst,
    const float* __restrict__ ode_w1, const float* __restrict__ ode_w2, const float* __restrict__ gru_wh,
    const float* __restrict__ act_w, const float* __restrict__ gru_wi,
    float* __restrict__ wh0_ws, float* __restrict__ sd_ws,
    ushort_t* __restrict__ w1B, ushort_t* __restrict__ w2B, ushort_t* __restrict__ ghB,
    ushort_t* __restrict__ actB, ushort_t* __restrict__ wiBt,
    ushort_t* __restrict__ fc_wB, ushort_t* __restrict__ gat_wB)
{
  __shared__ __align__(16) ushort_t xinB[16][392];
  __shared__ __align__(16) ushort_t xfcB[16][264];
  __shared__ float wh[16][132];
  const int tid = threadIdx.x;
  const int bt0 = blockIdx.x * 16;

  for (int p = blockIdx.x * 256 + tid; p < 280576; p += 128*256) {
    if (p < 49152) {
      int m = p >> 7, k = p & 127;
      ghB[p] = f2bf(gru_wh[k*384 + m]);
    } else if (p < 65536) {
      int q = p - 49152, jj = q >> 7, k = q & 127;
      w1B[q] = f2bf(ode_w1[k*128 + jj]);
    } else if (p < 81920) {
      int q = p - 65536, jj = q >> 7, k = q & 127;
      w2B[q] = f2bf(ode_w2[k*128 + jj]);
    } else if (p < 100352) {
      int q = p - 81920, col = q >> 7, k = q & 127;
      actB[q] = (col < 132) ? f2bf(act_w[k*132 + col]) : (ushort_t)0;
    } else if (p < 149504) {
      int q = p - 100352, m = q >> 7, f = q & 127;
      wiBt[q] = f2bf(gru_wi[f*384 + m]);
    } else if (p < 247808) {
      int q = p - 149504, col = q / 384, k = q - col*384;
      fc_wB[q] = f2bf(fc_w[k*256 + col]);
    } else {
      int q = p - 247808, col = q >> 8, k = q & 255;
      gat_wB[q] = f2bf(gat_w[k*128 + col]);
    }
  }

  for (int idx = tid; idx < 16*384; idx += 256) {
    int r = idx / 384, f = idx - r*384;
    xinB[r][f] = f2bf(inputs[(size_t)(bt0+r)*NIN + 10133 + f]);
  }
  __syncthreads();

  const int w = tid >> 6, lane = tid & 63;
  const int li = lane & 15, g = lane >> 4;

  // FC: xfc = relu(xin @ fc_w + fc_b)
  {
    bf16x8 afr[12];
    #pragma unroll
    for (int kt=0;kt<12;kt++)
      afr[kt] = *reinterpret_cast<const bf16x8*>(&xinB[li][kt*32 + g*8]);
    for (int ct = w*4; ct < w*4 + 4; ct++) {
      f32x4 acc = {0.f,0.f,0.f,0.f};
      #pragma unroll
      for (int kt=0;kt<12;kt++){
        bf16x8 bf = *reinterpret_cast<const bf16x8*>(fc_wB + (size_t)(ct*16+li)*384 + kt*32 + g*8);
        acc = __builtin_amdgcn_mfma_f32_16x16x32_bf16(afr[kt], bf, acc, 0,0,0);
      }
      const float bias = fc_b[ct*16 + li];
      #pragma unroll
      for (int r=0;r<4;r++)
        xfcB[g*4 + r][ct*16 + li] = f2bf(fmaxf(acc[r] + bias, 0.f));
    }
  }
  __syncthreads();

  // GAT: wh = xfc @ gat_w
  {
    bf16x8 afr[8];
    #pragma unroll
    for (int kt=0;kt<8;kt++)
      afr[kt] = *reinterpret_cast<const bf16x8*>(&xfcB[li][kt*32 + g*8]);
    for (int ct = w*2; ct < w*2 + 2; ct++) {
      f32x4 acc = {0.f,0.f,0.f,0.f};
      #pragma unroll
      for (int kt=0;kt<8;kt++){
        bf16x8 bf = *reinterpret_cast<const bf16x8*>(gat_wB + (size_t)(ct*16+li)*256 + kt*32 + g*8);
        acc = __builtin_amdgcn_mfma_f32_16x16x32_bf16(afr[kt], bf, acc, 0,0,0);
      }
      #pragma unroll
      for (int r=0;r<4;r++){
        const int row = g*4 + r, col = ct*16 + li;
        wh[row][col] = acc[r];
        wh0_ws[(size_t)(bt0+row)*128 + col] = acc[r];
      }
    }
  }
  __syncthreads();

  if (tid < 128) {
    const int r = tid >> 3, h = (tid >> 1) & 3, wv = tid & 1;
    const float* av = wv ? a_dst : a_src;
    float acc = 0.f;
    #pragma unroll
    for (int d=0; d<32; d++) acc = fmaf(wh[r][h*32+d], av[h*32+d], acc);
    sd_ws[(size_t)(bt0+r)*8 + wv*4 + h] = acc;
  }
}

// ---------------- K1b: adjacency stats + closed-form alpha + x_gat (bf16 out) ----------------
__global__ __launch_bounds__(256) void k_alpha_gi(const float* __restrict__ inputs,
    const float* __restrict__ wh0_ws, const float* __restrict__ sd_ws,
    ushort_t* __restrict__ xg_bf)
{
  __shared__ int cnt[100];
  __shared__ int a0f[100];
  __shared__ float alpha[4][100];
  __shared__ float wh0[128];
  __shared__ float sdl[8];
  __shared__ float psum[256];
  const int tid = threadIdx.x;
  const size_t bt = blockIdx.x;
  if (tid < 128) wh0[tid] = wh0_ws[bt*128 + tid];
  if (tid < 8) sdl[tid] = sd_ws[bt*8 + tid];
  const float* adj = inputs + bt*NIN + 132;
  const int wv = tid >> 6, lane = tid & 63;
  for (int i = wv; i < 100; i += 4) {
    float v0 = adj[i*100 + lane];
    int pred0 = (lane != 0) && ((v0 > 0.f) || (lane == i));
    unsigned long long b0 = __ballot(pred0);
    int pred1 = 0;
    if (lane < 36) {
      float v1 = adj[i*100 + 64 + lane];
      pred1 = (v1 > 0.f) || ((64 + lane) == i);
    }
    unsigned long long b1 = __ballot(pred1);
    if (lane == 0) {
      cnt[i] = __popcll(b0) + __popcll(b1);
      a0f[i] = (v0 > 0.f) ? 1 : 0;
    }
  }
  __syncthreads();
  for (int idx = tid; idx < 400; idx += 256) {
    int h = idx / 100, i = idx - h*100;
    float s = sdl[h], d = sdl[4+h];
    float a;
    if (i == 0) {
      float ea = __expf(lrelu02(s + d));
      float eb = __expf(lrelu02(s));
      a = ea / (ea + (float)cnt[0] * eb);
    } else if (a0f[i]) {
      float ed = __expf(lrelu02(d));
      a = ed / (ed + (float)cnt[i]);
    } else {
      a = 0.f;
    }
    alpha[h][i] = a;
  }
  __syncthreads();
  {
    const int pr = tid & 127, hf = tid >> 7;
    const float w = wh0[pr];
    const int hh = pr >> 5;
    float sum = 0.f;
    const int i0 = hf * 50;
    for (int i = i0; i < i0 + 50; i++) {
      float t = alpha[hh][i] * w;
      sum += (t > 0.f) ? t : (__expf(t) - 1.f);
    }
    psum[tid] = sum;
  }
  __syncthreads();
  if (tid < 128) xg_bf[bt*128 + tid] = f2bf((psum[tid] + psum[tid+128]) * 0.01f);
}

// ---------------- K1c: gi = xg @ gru_wi + bi as MFMA GEMM (2048x384x128) ----------------
__global__ __launch_bounds__(256) void k_gi(const ushort_t* __restrict__ xg_bf,
    const ushort_t* __restrict__ wiBt, const float* __restrict__ gru_bi,
    float* __restrict__ gi_ws)
{
  const int tid = threadIdx.x;
  const int w = tid >> 6, lane = tid & 63;
  const int li = lane & 15, g = lane >> 4;
  const int bt0 = blockIdx.x * 16;
  bf16x8 haf[4];
  #pragma unroll
  for (int kt=0;kt<4;kt++)
    haf[kt] = *reinterpret_cast<const bf16x8*>(xg_bf + ((size_t)(bt0 + li))*128 + kt*32 + g*8);
  for (int ct = w*6; ct < w*6 + 6; ct++) {
    const int m = ct*16 + li;
    const f32x4 z0 = {0.f,0.f,0.f,0.f};
    const ushort_t* wb = wiBt + (size_t)m*128;
    bf16x8 b0 = *reinterpret_cast<const bf16x8*>(wb + 0*32 + g*8);
    bf16x8 b1f = *reinterpret_cast<const bf16x8*>(wb + 1*32 + g*8);
    bf16x8 b2f = *reinterpret_cast<const bf16x8*>(wb + 2*32 + g*8);
    bf16x8 b3f = *reinterpret_cast<const bf16x8*>(wb + 3*32 + g*8);
    f32x4 c0 = __builtin_amdgcn_mfma_f32_16x16x32_bf16(haf[0], b0,  z0, 0,0,0);
    f32x4 c1 = __builtin_amdgcn_mfma_f32_16x16x32_bf16(haf[1], b1f, z0, 0,0,0);
    f32x4 c2 = __builtin_amdgcn_mfma_f32_16x16x32_bf16(haf[2], b2f, z0, 0,0,0);
    f32x4 c3 = __builtin_amdgcn_mfma_f32_16x16x32_bf16(haf[3], b3f, z0, 0,0,0);
    const float bim = gru_bi[m];
    #pragma unroll
    for (int r=0;r<4;r++)
      gi_ws[(size_t)(bt0 + g*4 + r)*384 + m] = ((c0[r]+c1[r]) + (c2[r]+c3[r])) + bim;
  }
}

// ---------------- K2: RK4-ODE + GRU scan via MFMA + fused output heads (r14/r18/r19 frozen) ----------------
// Empirical optimum of this structure (147.1us). Perturbation ledger: weight
// residency via VGPR pin (r8/r9), AGPR (r15), LDS (r16), and 1-phase-ahead
// prefetch (r20) ALL regressed; gi via LDS (r17) regressed. Do not touch
// the loop body without per-phase instrumentation.
__global__ __launch_bounds__(512) void k_rnn(const float* __restrict__ inputs,
    const float* __restrict__ h0,
    const ushort_t* __restrict__ w1B, const float* __restrict__ ode_b1,
    const ushort_t* __restrict__ w2B, const float* __restrict__ ode_b2,
    const ushort_t* __restrict__ ghB, const float* __restrict__ gru_bh,
    const ushort_t* __restrict__ actB, const float* __restrict__ act_b,
    const float* __restrict__ val_w, const float* __restrict__ val_b,
    const float* __restrict__ gi_ws,
    float* __restrict__ out_logits, float* __restrict__ out_hT, float* __restrict__ out_val)
{
  __shared__ __align__(16) ushort_t bufA[128];
  __shared__ __align__(16) ushort_t bufB[128];
  __shared__ __align__(16) ushort_t bufC[128];
  __shared__ float dtbuf[64];
  __shared__ __align__(16) ushort_t hsbuf[64*136];   // rows padded 128->136
  const int tid = threadIdx.x;
  const int b = blockIdx.x;
  const int w = tid >> 6, lane = tid & 63;
  const int li = lane & 15, g = lane >> 4;
  const int col = w*16 + li;                 // output column (x4 replicated over g)

  bf16x8 W1f[4], W2f[4], GAf[4], GBf[4], GCf[4];
  #pragma unroll
  for (int kt=0;kt<4;kt++){
    const int o = kt*32 + g*8;
    W1f[kt] = *reinterpret_cast<const bf16x8*>(w1B + col*128 + o);
    W2f[kt] = *reinterpret_cast<const bf16x8*>(w2B + col*128 + o);
    GAf[kt] = *reinterpret_cast<const bf16x8*>(ghB + (size_t)col*128       + o);
    GBf[kt] = *reinterpret_cast<const bf16x8*>(ghB + (size_t)(col+128)*128 + o);
    GCf[kt] = *reinterpret_cast<const bf16x8*>(ghB + (size_t)(col+256)*128 + o);
  }
  const float b1 = ode_b1[col], b2 = ode_b2[col];
  const float bh0 = gru_bh[col], bh1 = gru_bh[col+128], bh2 = gru_bh[col+256];
  float h = h0[b*128 + col];
  if (tid < 64) dtbuf[tid] = inputs[((size_t)b*64 + tid)*NIN + 10132];
  if (lane < 16) bufC[col] = f2bf(h);
  const float* gib = gi_ws + (size_t)b*64*384 + col;
  __syncthreads();

  bf16x8 af[4];
  auto ldaf = [&](const ushort_t* __restrict__ hb){
    #pragma unroll
    for (int kt=0;kt<4;kt++) af[kt] = *reinterpret_cast<const bf16x8*>(hb + kt*32 + g*8);
  };
  auto mvac = [&](const bf16x8 (&Wf)[4])->float{
    const f32x4 z0 = {0.f,0.f,0.f,0.f};
    f32x4 c0 = __builtin_amdgcn_mfma_f32_16x16x32_bf16(af[0], Wf[0], z0, 0,0,0);
    f32x4 c1 = __builtin_amdgcn_mfma_f32_16x16x32_bf16(af[1], Wf[1], z0, 0,0,0);
    f32x4 c2 = __builtin_amdgcn_mfma_f32_16x16x32_bf16(af[2], Wf[2], z0, 0,0,0);
    f32x4 c3 = __builtin_amdgcn_mfma_f32_16x16x32_bf16(af[3], Wf[3], z0, 0,0,0);
    return (c0[0]+c1[0]) + (c2[0]+c3[0]);
  };

  for (int t=0; t<64; t++) {
    const float dt = dtbuf[t];
    const float gir = gib[(size_t)t*384];
    const float giz = gib[(size_t)t*384 + 128];
    const float gin = gib[(size_t)t*384 + 256];

    float u, k1, k2, k3, k4;
    ldaf(bufC); u  = fast_tanh(mvac(W1f)+b1); if (lane<16) bufA[col]=f2bf(u);                    LBAR();
    ldaf(bufA); k1 = fast_tanh(mvac(W2f)+b2); if (lane<16) bufB[col]=f2bf(fmaf(0.5f*dt,k1,h));   LBAR();
    ldaf(bufB); u  = fast_tanh(mvac(W1f)+b1); if (lane<16) bufA[col]=f2bf(u);                    LBAR();
    ldaf(bufA); k2 = fast_tanh(mvac(W2f)+b2); if (lane<16) bufB[col]=f2bf(fmaf(0.5f*dt,k2,h));   LBAR();
    ldaf(bufB); u  = fast_tanh(mvac(W1f)+b1); if (lane<16) bufA[col]=f2bf(u);                    LBAR();
    ldaf(bufA); k3 = fast_tanh(mvac(W2f)+b2); if (lane<16) bufB[col]=f2bf(fmaf(dt,k3,h));        LBAR();
    ldaf(bufB); u  = fast_tanh(mvac(W1f)+b1); if (lane<16) bufA[col]=f2bf(u);                    LBAR();
    ldaf(bufA); k4 = fast_tanh(mvac(W2f)+b2);
    const float h_ode = fmaf(dt*(1.f/6.f), (k1 + 2.f*k2) + (2.f*k3 + k4), h);
    if (lane<16) bufB[col] = f2bf(h_ode);                                                        LBAR();

    ldaf(bufB);
    {
      const float r = fast_sig(gir + mvac(GAf) + bh0);
      const float z = fast_sig(giz + mvac(GBf) + bh1);
      const float n = fast_tanh(gin + r*(mvac(GCf) + bh2));
      h = (1.f - z)*n + z*h_ode;
    }
    if (lane < 16) {
      bufC[col] = f2bf(h);
      hsbuf[t*136 + col] = f2bf(h);
    }
    LBAR();
  }

  if (lane < 16) out_hT[b*128 + col] = h;

  // ---- epilogue: logits via MFMA GEMM (64x132 = hs @ act_w) ----
  {
    const int rt = w & 3, ch = w >> 2;
    const int r0 = rt*16;
    bf16x8 haf[4];
    #pragma unroll
    for (int kt=0;kt<4;kt++)
      haf[kt] = *reinterpret_cast<const bf16x8*>(hsbuf + (r0+li)*136 + kt*32 + g*8);
    const int ct0 = ch ? 5 : 0, ctN = ch ? 9 : 5;
    for (int ct=ct0; ct<ctN; ct++){
      const f32x4 z0 = {0.f,0.f,0.f,0.f};
      f32x4 c0, c1, c2, c3;
      {
        const ushort_t* ab = actB + (size_t)(ct*16+li)*128;
        bf16x8 b0 = *reinterpret_cast<const bf16x8*>(ab + 0*32 + g*8);
        bf16x8 b1f = *reinterpret_cast<const bf16x8*>(ab + 1*32 + g*8);
        bf16x8 b2f = *reinterpret_cast<const bf16x8*>(ab + 2*32 + g*8);
        bf16x8 b3f = *reinterpret_cast<const bf16x8*>(ab + 3*32 + g*8);
        c0 = __builtin_amdgcn_mfma_f32_16x16x32_bf16(haf[0], b0,  z0, 0,0,0);
        c1 = __builtin_amdgcn_mfma_f32_16x16x32_bf16(haf[1], b1f, z0, 0,0,0);
        c2 = __builtin_amdgcn_mfma_f32_16x16x32_bf16(haf[2], b2f, z0, 0,0,0);
        c3 = __builtin_amdgcn_mfma_f32_16x16x32_bf16(haf[3], b3f, z0, 0,0,0);
      }
      const int colL = ct*16 + li;
      if (colL < 132){
        const float ab = act_b[colL];
        #pragma unroll
        for (int reg=0; reg<4; reg++){
          const int r = r0 + g*4 + reg;
          const size_t bt = (size_t)b*64 + r;
          const float mval = inputs[bt*NIN + colL];
          const float v = ((c0[reg]+c1[reg]) + (c2[reg]+c3[reg])) + ab;
          out_logits[bt*132 + colL] = (mval == 0.f) ? -1e10f : v;
        }
      }
    }
  }
  // ---- epilogue: value head ----
  if (tid < 64){
    float acc = val_b[0];
    for (int k=0;k<128;k++) acc = fmaf(bf2f(hsbuf[tid*136 + k]), val_w[k], acc);
    out_val[b*64 + tid] = acc;
  }
}

extern "C" void kernel_launch(void* const* d_in, const int* in_sizes, int n_in,
                              void* d_out, int out_size, void* d_ws, size_t ws_size,
                              hipStream_t stream) {
  (void)in_sizes; (void)n_in; (void)out_size; (void)ws_size;
  const float* inputs = (const float*)d_in[0];
  const float* h0     = (const float*)d_in[1];
  const float* fc_w   = (const float*)d_in[2];
  const float* fc_b   = (const float*)d_in[3];
  const float* gat_w  = (const float*)d_in[4];
  const float* a_src  = (const float*)d_in[5];
  const float* a_dst  = (const float*)d_in[6];
  const float* ode_w1 = (const float*)d_in[7];
  const float* ode_b1 = (const float*)d_in[8];
  const float* ode_w2 = (const float*)d_in[9];
  const float* ode_b2 = (const float*)d_in[10];
  const float* gru_wi = (const float*)d_in[11];
  const float* gru_wh = (const float*)d_in[12];
  const float* gru_bi = (const float*)d_in[13];
  const float* gru_bh = (const float*)d_in[14];
  const float* act_w  = (const float*)d_in[15];
  const float* act_b  = (const float*)d_in[16];
  const float* val_w  = (const float*)d_in[17];
  const float* val_b  = (const float*)d_in[18];

  float* ws   = (float*)d_ws;
  float* wh0  = ws;                              // 262144 floats
  float* sd   = ws + 262144;                     // 16384
  ushort_t* xg_bf = (ushort_t*)(ws + 278528);    // 262144 ush
  float* gi   = ws + 409600;                     // 786432 fl
  ushort_t* w1B   = (ushort_t*)(ws + 1196032);   // 16384 ush
  ushort_t* w2B   = (ushort_t*)(ws + 1204224);   // 16384 ush
  ushort_t* ghB   = (ushort_t*)(ws + 1212416);   // 49152 ush
  ushort_t* actB  = (ushort_t*)(ws + 1236992);   // 18432 ush
  ushort_t* wiBt  = (ushort_t*)(ws + 1246208);   // 49152 ush
  ushort_t* fc_wB = (ushort_t*)(ws + 1270784);   // 98304 ush
  ushort_t* gat_wB= (ushort_t*)(ws + 1319936);   // 32768 ush

  float* out        = (float*)d_out;
  float* out_logits = out;            // 2048*132
  float* out_hT     = out + 270336;   // 32*128
  float* out_val    = out + 274432;   // 2048

  k_fc_gat  <<<dim3(128),  dim3(256), 0, stream>>>(inputs, fc_w, fc_b, gat_w, a_src, a_dst,
                                                   ode_w1, ode_w2, gru_wh, act_w, gru_wi,
                                                   wh0, sd, w1B, w2B, ghB, actB, wiBt,
                                                   fc_wB, gat_wB);
  k_alpha_gi<<<dim3(2048), dim3(256), 0, stream>>>(inputs, wh0, sd, xg_bf);
  k_gi      <<<dim3(128),  dim3(256), 0, stream>>>(xg_bf, wiBt, gru_bi, gi);
  k_rnn     <<<dim3(32),   dim3(512), 0, stream>>>(inputs, h0, w1B, ode_b1, w2B, ode_b2,
                                                   ghB, gru_bh, actB, act_b, val_w, val_b,
                                                   gi, out_logits, out_hT, out_val);
}